// Round 5
// baseline (636.636 us; speedup 1.0000x reference)
//
#include <hip/hip_runtime.h>

namespace {

constexpr int B = 16, C = 3, H = 512, W = 1024;
constexpr int HW = H * W;               // 2^19
constexpr int TW = 128, TH = 32;        // tile
constexpr int HALO = 32;
constexpr int SW = TW + 2 * HALO;       // 192 staged width
constexpr int SH = TH + 2 * HALO;       // 96  staged height
constexpr int SWP = SW + 4;             // 196 padded LDS stride (bank spread + float4 align)
constexpr int BLOCK = 512;
constexpr int PXT = (TW * TH) / BLOCK;  // 8 pixels per thread
constexpr int GRID = B * (W / TW) * (H / TH);  // 16*8*16 = 2048

__global__ __launch_bounds__(BLOCK, 4) void flow_loss_partial(
    const float* __restrict__ flow,   // (B,H,W,2)
    const float* __restrict__ im1,    // (B,C,H,W)
    const float* __restrict__ im2,    // (B,C,H,W)
    float* __restrict__ partials)     // [GRID]
{
    __shared__ float smem[SH * SWP];      // 75264 B -> 2 blocks/CU
    __shared__ float red[BLOCK / 64];

    const int tid = threadIdx.x;
    const int bid = blockIdx.x;
    const int b   = bid >> 7;             // 128 tiles per image
    const int tt  = bid & 127;
    const int ty  = tt >> 3;              // 16 tile-rows
    const int tx  = tt & 7;               // 8 tile-cols
    const int yTile = ty * TH, xTile = tx * TW;
    const int yBase = yTile - HALO, xBase = xTile - HALO;

    // ---------------- phase 0: per-pixel geometry (registers) ----------------
    int   offT[PXT], offB[PXT];           // LDS byte offsets; sign bit => global fallback
    float aT0[PXT], aT1[PXT], aB0[PXT], aB1[PXT];

#pragma unroll
    for (int p = 0; p < PXT; ++p) {
        const int idx = p * BLOCK + tid;  // 0..4095 within tile
        const int row = idx >> 7;         // TW = 128
        const int col = idx & (TW - 1);
        const int x = xTile + col, y = yTile + row;

        const float2 f = *reinterpret_cast<const float2*>(flow + 2 * (b * HW + (y << 10) + x));

        // replicate reference arithmetic sequence exactly (f32)
        const float base_x = (float)x / (float)W * 2.0f - 1.0f;
        const float base_y = (float)y / (float)H * 2.0f - 1.0f;
        const float gx = f.x / (float)W + base_x;
        const float gy = f.y / (float)H + base_y;
        const float ix = ((gx + 1.0f) * (float)W - 1.0f) * 0.5f;
        const float iy = ((gy + 1.0f) * (float)H - 1.0f) * 0.5f;

        const float x0f = floorf(ix), y0f = floorf(iy);
        const float wx1 = ix - x0f, wx0 = 1.0f - wx1;
        const float wy1 = iy - y0f, wy0 = 1.0f - wy1;

        const int x0 = (int)x0f, y0 = (int)y0f;
        const int x1 = x0 + 1,   y1 = y0 + 1;

        const bool vx0 = (x0 >= 0) & (x0 < W);
        const bool vx1 = (x1 >= 0) & (x1 < W);
        const bool vy0 = (y0 >= 0) & (y0 < H);
        const bool vy1 = (y1 >= 0) & (y1 < H);

        const float w00 = wx0 * wy0 * (float)(vx0 & vy0);
        const float w01 = wx1 * wy0 * (float)(vx1 & vy0);
        const float w10 = wx0 * wy1 * (float)(vx0 & vy1);
        const float w11 = wx1 * wy1 * (float)(vx1 & vy1);

        const int xL  = min(max(x0, 0), W - 2);
        const int x0c = min(max(x0, 0), W - 1);
        const int x1c = min(max(x1, 0), W - 1);
        const int y0c = min(max(y0, 0), H - 1);
        const int y1c = min(max(y1, 0), H - 1);
        const bool s0 = (x0c != xL);      // corner x0 selects .y half
        const bool s1 = (x1c != xL);      // corner x1 selects .y half

        // fold the .x/.y select into the weights (exact: one term is 0.0f
        // whenever the clamp breaks adjacency — see round-4 edge analysis)
        aT0[p] = (s0 ? 0.0f : w00) + (s1 ? 0.0f : w01);
        aT1[p] = (s0 ? w00 : 0.0f) + (s1 ? w01 : 0.0f);
        aB0[p] = (s0 ? 0.0f : w10) + (s1 ? 0.0f : w11);
        aB1[p] = (s0 ? w10 : 0.0f) + (s1 ? w11 : 0.0f);

        const int rT = y0c - yBase;       // staged row of top pair
        const int rB = y1c - yBase;       // staged row of bottom pair
        const int cl = xL  - xBase;       // staged col of pair
        const bool ok = ((unsigned)rT < (unsigned)SH) &
                        ((unsigned)rB < (unsigned)SH) &
                        ((unsigned)cl <= (unsigned)(SW - 2));
        if (ok) {
            offT[p] = 4 * (rT * SWP + cl);
            offB[p] = 4 * (rB * SWP + cl);
        } else {                           // ~never (needs |flow| > ~7.5 sigma)
            offT[p] = (int)0x80000000 | (4 * (y0c * W + xL));
            offB[p] = (int)0x80000000 | (4 * (y1c * W + xL));
        }
    }

    const bool colOK = (xBase >= 0) && (xBase + SW <= W);
    float acc = 0.0f;

    // ---------------- per-channel: stage -> resolve ----------------
    for (int c = 0; c < C; ++c) {
        const float* __restrict__ imc  = im1 + (b * C + c) * HW;
        const float* __restrict__ im2c = im2 + (b * C + c) * HW;

        __syncthreads();                  // previous channel's reads done

        if (colOK) {
            // 96 rows x 48 float4 = 4608 vec4s; 9 per thread, coalesced
#pragma unroll
            for (int k = 0; k < (SH * SW / 4) / BLOCK; ++k) {
                const int s4 = k * BLOCK + tid;
                const int r  = s4 / 48;
                const int c4 = s4 - r * 48;
                const int yc = min(max(yBase + r, 0), H - 1);
                const float4 v = *reinterpret_cast<const float4*>(imc + yc * W + xBase + (c4 << 2));
                *reinterpret_cast<float4*>(smem + r * SWP + (c4 << 2)) = v;
            }
        } else {
            // clamped scalar path (tx == 0 or 7)
#pragma unroll
            for (int k = 0; k < (SH * SW) / BLOCK; ++k) {
                const int s  = k * BLOCK + tid;
                const int r  = s / SW;
                const int cc = s - r * SW;
                const int yc = min(max(yBase + r, 0), H - 1);
                const int xc = min(max(xBase + cc, 0), W - 1);
                smem[r * SWP + cc] = imc[yc * W + xc];
            }
        }

        __syncthreads();

        // issue the coalesced im2 loads for all pixels first
        float z[PXT];
#pragma unroll
        for (int p = 0; p < PXT; ++p) {
            const int idx = p * BLOCK + tid;
            const int row = idx >> 7;
            const int col = idx & (TW - 1);
            z[p] = im2c[((yTile + row) << 10) + xTile + col];
        }

#pragma unroll
        for (int p = 0; p < PXT; ++p) {
            const int ot = offT[p];
            float wp;
            if (ot >= 0) {
                const float* lT = reinterpret_cast<const float*>(
                    reinterpret_cast<const char*>(smem) + ot);
                const float* lB = reinterpret_cast<const float*>(
                    reinterpret_cast<const char*>(smem) + offB[p]);
                const float t0 = lT[0], t1 = lT[1];
                const float b0 = lB[0], b1 = lB[1];
                wp = ((aT0[p] * t0 + aT1[p] * t1) + aB0[p] * b0) + aB1[p] * b1;
            } else {
                const float* gT = reinterpret_cast<const float*>(
                    reinterpret_cast<const char*>(imc) + (ot & 0x7fffffff));
                const float* gB = reinterpret_cast<const float*>(
                    reinterpret_cast<const char*>(imc) + (offB[p] & 0x7fffffff));
                const float t0 = gT[0], t1 = gT[1];
                const float b0 = gB[0], b1 = gB[1];
                wp = ((aT0[p] * t0 + aT1[p] * t1) + aB0[p] * b0) + aB1[p] * b1;
            }
            acc += fabsf(z[p] - wp);
        }
    }

    // ---------------- block reduction ----------------
#pragma unroll
    for (int o = 32; o > 0; o >>= 1)
        acc += __shfl_down(acc, o, 64);

    const int lane = tid & 63;
    const int wid  = tid >> 6;
    if (lane == 0) red[wid] = acc;
    __syncthreads();
    if (tid == 0) {
        float s = 0.0f;
#pragma unroll
        for (int wv = 0; wv < BLOCK / 64; ++wv) s += red[wv];
        partials[bid] = s;
    }
}

__global__ __launch_bounds__(256) void flow_loss_reduce(
    const float* __restrict__ partials, float* __restrict__ out)
{
    __shared__ double lds[256];
    double s = 0.0;
    for (int i = threadIdx.x; i < GRID; i += 256) s += (double)partials[i];
    lds[threadIdx.x] = s;
    __syncthreads();
    for (int o = 128; o > 0; o >>= 1) {
        if (threadIdx.x < o) lds[threadIdx.x] += lds[threadIdx.x + o];
        __syncthreads();
    }
    if (threadIdx.x == 0) out[0] = (float)(lds[0] / (double)(W * H));
}

} // namespace

extern "C" void kernel_launch(void* const* d_in, const int* in_sizes, int n_in,
                              void* d_out, int out_size, void* d_ws, size_t ws_size,
                              hipStream_t stream) {
    const float* flow = (const float*)d_in[0];
    const float* im1  = (const float*)d_in[1];
    const float* im2  = (const float*)d_in[2];
    float* out = (float*)d_out;
    float* partials = (float*)d_ws;

    flow_loss_partial<<<GRID, BLOCK, 0, stream>>>(flow, im1, im2, partials);
    flow_loss_reduce<<<1, 256, 0, stream>>>(partials, out);
}

// Round 6
// 70.372 us; speedup vs baseline: 9.0468x; 9.0468x over previous
//
#include <hip/hip_runtime.h>

namespace {

constexpr int B = 16, C = 3, H = 512, W = 1024;
constexpr int HW = H * W;               // 2^19
constexpr int SLABW = 256, SLABH = 128;
constexpr int XH  = 16;                 // x halo
constexpr int SWD = SLABW + 2 * XH;     // 288 staged cols
constexpr int PADW = SWD + 4;           // 292 LDS stride (292 % 32 = 4 -> bank spread)
constexpr int RING = 32;                // ring rows (power of 2)
constexpr int RA = 12;                  // rows behind
constexpr int RB = 16;                  // rows ahead
constexpr int RPS = 4;                  // rows per step
constexpr int BLOCK = 1024;
constexpr int TX = W / SLABW;           // 4
constexpr int TY = H / SLABH;           // 4
constexpr int GRID = B * TX * TY;       // 256 blocks = 1/CU
constexpr int PF_ROWS = RA + RB + 1;    // 29 prefill rows
constexpr int STG_N = C * RPS * SWD;    // 3456 staged elems / step

// 4B-aligned float2 (adjacent-corner pair at arbitrary dword offset)
__device__ __forceinline__ float2 ld2g(const float* p) {
    struct __attribute__((packed, aligned(4))) F2 { float a, b; };
    const F2 v = *reinterpret_cast<const F2*>(p);
    return make_float2(v.a, v.b);
}

__global__ __launch_bounds__(BLOCK, 4) void flow_loss_partial(
    const float* __restrict__ flow,   // (B,H,W,2)
    const float* __restrict__ im1,    // (B,C,H,W)
    const float* __restrict__ im2,    // (B,C,H,W)
    float* __restrict__ partials)     // [GRID]
{
    __shared__ float smem[C * RING * PADW];   // 112128 B
    __shared__ float red[BLOCK / 64];

    const int tid = threadIdx.x;
    const int bid = blockIdx.x;
    const int b   = bid >> 4;                 // 16 slabs per image
    const int tt  = bid & 15;
    const int tyi = tt >> 2;
    const int txi = tt & 3;
    const int xbase  = txi * SLABW;
    const int yStart = tyi * SLABH;

    const float* __restrict__ im1b = im1 + b * C * HW;
    const float* __restrict__ im2b = im2 + b * C * HW;
    const float* __restrict__ flb  = flow + 2 * (b * HW);

    // ---------------- prefill ring: rows yStart-RA .. yStart+RB ----------------
    for (int e = tid; e < PF_ROWS * C * SWD; e += BLOCK) {
        const int scol = e % SWD;
        const int rc   = e / SWD;             // 0..86
        const int c    = rc / PF_ROWS;
        const int ri   = rc - c * PF_ROWS;
        const int row  = yStart - RA + ri;
        if (row >= 0) {                       // row <= yStart+RB < H always
            const int gcol = min(max(xbase - XH + scol, 0), W - 1);
            smem[(c * RING + (row & (RING - 1))) * PADW + scol] =
                im1b[c * HW + row * W + gcol];
        }
    }
    __syncthreads();

    const int colp = tid & (SLABW - 1);
    const int prow = tid >> 8;                // 0..3
    const int x = xbase + colp;

    float acc = 0.0f;

#pragma unroll 1
    for (int ys = yStart; ys < yStart + SLABH; ys += RPS) {
        // ---- (a) issue staging loads (rows ys+RB+1 .. ys+RB+RPS) into regs ----
        int   sIdx[4];
        float sVal[4];
#pragma unroll
        for (int k = 0; k < 4; ++k) {
            const int e = k * BLOCK + tid;
            int idx = -1; float v = 0.0f;
            if (e < STG_N) {
                const int scol = e % SWD;
                const int rc   = e / SWD;     // 0..11
                const int c    = rc >> 2;
                const int sr   = rc & 3;
                const int srow = ys + RB + 1 + sr;
                if (srow < H) {
                    const int gcol = min(max(xbase - XH + scol, 0), W - 1);
                    v   = im1b[c * HW + srow * W + gcol];
                    idx = (c * RING + (srow & (RING - 1))) * PADW + scol;
                }
            }
            sIdx[k] = idx; sVal[k] = v;
        }

        // ---- (b) compute this thread's pixel ----
        const int y = ys + prow;
        const float2 f = *reinterpret_cast<const float2*>(flb + 2 * (y * W + x));

        // replicate reference arithmetic sequence exactly (f32)
        const float base_x = (float)x / (float)W * 2.0f - 1.0f;
        const float base_y = (float)y / (float)H * 2.0f - 1.0f;
        const float gx = f.x / (float)W + base_x;
        const float gy = f.y / (float)H + base_y;
        const float ixf = ((gx + 1.0f) * (float)W - 1.0f) * 0.5f;
        const float iyf = ((gy + 1.0f) * (float)H - 1.0f) * 0.5f;
        const float x0f = floorf(ixf), y0f = floorf(iyf);
        const float wx1 = ixf - x0f, wx0 = 1.0f - wx1;
        const float wy1 = iyf - y0f, wy0 = 1.0f - wy1;
        const int x0 = (int)x0f, y0 = (int)y0f;
        const int x1 = x0 + 1,   y1 = y0 + 1;
        const bool vx0 = (x0 >= 0) & (x0 < W);
        const bool vx1 = (x1 >= 0) & (x1 < W);
        const bool vy0 = (y0 >= 0) & (y0 < H);
        const bool vy1 = (y1 >= 0) & (y1 < H);
        const float w00 = wx0 * wy0 * (float)(vx0 & vy0);
        const float w01 = wx1 * wy0 * (float)(vx1 & vy0);
        const float w10 = wx0 * wy1 * (float)(vx0 & vy1);
        const float w11 = wx1 * wy1 * (float)(vx1 & vy1);
        const int xL  = min(max(x0, 0), W - 2);
        const int x0c = min(max(x0, 0), W - 1);
        const int x1c = min(max(x1, 0), W - 1);
        const int y0c = min(max(y0, 0), H - 1);
        const int y1c = min(max(y1, 0), H - 1);
        const bool s0 = (x0c != xL), s1 = (x1c != xL);
        // fold .x/.y select into weights (exact: selected-away term is 0.0f)
        const float aT0 = (s0 ? 0.0f : w00) + (s1 ? 0.0f : w01);
        const float aT1 = (s0 ? w00 : 0.0f) + (s1 ? w01 : 0.0f);
        const float aB0 = (s0 ? 0.0f : w10) + (s1 ? 0.0f : w11);
        const float aB1 = (s0 ? w10 : 0.0f) + (s1 ? w11 : 0.0f);

        const int jj = xL - xbase + XH;
        const bool inR = (y0c >= ys - RA) & (y1c <= ys + RB) &
                         ((unsigned)jj <= (unsigned)(SWD - 2));

        const int zoff = y * W + x;
        const float z0 = im2b[zoff];
        const float z1 = im2b[HW + zoff];
        const float z2 = im2b[2 * HW + zoff];

        float wp0, wp1, wp2;
        if (inR) {
            const int lT = (y0c & (RING - 1)) * PADW + jj;
            const int lB = (y1c & (RING - 1)) * PADW + jj;
            const float t00 = smem[lT],                  t01 = smem[lT + 1];
            const float b00 = smem[lB],                  b01 = smem[lB + 1];
            const float t10 = smem[RING * PADW + lT],    t11 = smem[RING * PADW + lT + 1];
            const float b10 = smem[RING * PADW + lB],    b11 = smem[RING * PADW + lB + 1];
            const float t20 = smem[2 * RING * PADW + lT], t21 = smem[2 * RING * PADW + lT + 1];
            const float b20 = smem[2 * RING * PADW + lB], b21 = smem[2 * RING * PADW + lB + 1];
            wp0 = ((aT0 * t00 + aT1 * t01) + aB0 * b00) + aB1 * b01;
            wp1 = ((aT0 * t10 + aT1 * t11) + aB0 * b10) + aB1 * b11;
            wp2 = ((aT0 * t20 + aT1 * t21) + aB0 * b20) + aB1 * b21;
        } else {                              // rare (~0.3%/px): exact global path
            const int oT = y0c * W + xL, oB = y1c * W + xL;
            const float2 ta = ld2g(im1b + oT),            ba = ld2g(im1b + oB);
            const float2 tb = ld2g(im1b + HW + oT),       bb = ld2g(im1b + HW + oB);
            const float2 tc = ld2g(im1b + 2 * HW + oT),   bc = ld2g(im1b + 2 * HW + oB);
            wp0 = ((aT0 * ta.x + aT1 * ta.y) + aB0 * ba.x) + aB1 * ba.y;
            wp1 = ((aT0 * tb.x + aT1 * tb.y) + aB0 * bb.x) + aB1 * bb.y;
            wp2 = ((aT0 * tc.x + aT1 * tc.y) + aB0 * bc.x) + aB1 * bc.y;
        }
        acc += fabsf(z0 - wp0) + fabsf(z1 - wp1) + fabsf(z2 - wp2);

        // ---- (c) all ring reads done; (d) commit staged rows ----
        __syncthreads();
#pragma unroll
        for (int k = 0; k < 4; ++k)
            if (sIdx[k] >= 0) smem[sIdx[k]] = sVal[k];
        __syncthreads();
    }

    // ---------------- block reduction ----------------
#pragma unroll
    for (int o = 32; o > 0; o >>= 1)
        acc += __shfl_down(acc, o, 64);
    const int lane = tid & 63;
    const int wid  = tid >> 6;
    if (lane == 0) red[wid] = acc;
    __syncthreads();
    if (tid == 0) {
        float s = 0.0f;
#pragma unroll
        for (int wv = 0; wv < BLOCK / 64; ++wv) s += red[wv];
        partials[bid] = s;
    }
}

__global__ __launch_bounds__(256) void flow_loss_reduce(
    const float* __restrict__ partials, float* __restrict__ out)
{
    __shared__ double lds[256];
    double s = 0.0;
    for (int i = threadIdx.x; i < GRID; i += 256) s += (double)partials[i];
    lds[threadIdx.x] = s;
    __syncthreads();
    for (int o = 128; o > 0; o >>= 1) {
        if (threadIdx.x < o) lds[threadIdx.x] += lds[threadIdx.x + o];
        __syncthreads();
    }
    if (threadIdx.x == 0) out[0] = (float)(lds[0] / (double)(W * H));
}

} // namespace

extern "C" void kernel_launch(void* const* d_in, const int* in_sizes, int n_in,
                              void* d_out, int out_size, void* d_ws, size_t ws_size,
                              hipStream_t stream) {
    const float* flow = (const float*)d_in[0];
    const float* im1  = (const float*)d_in[1];
    const float* im2  = (const float*)d_in[2];
    float* out = (float*)d_out;
    float* partials = (float*)d_ws;

    flow_loss_partial<<<GRID, BLOCK, 0, stream>>>(flow, im1, im2, partials);
    flow_loss_reduce<<<1, 256, 0, stream>>>(partials, out);
}

// Round 7
// 67.249 us; speedup vs baseline: 9.4669x; 1.0464x over previous
//
#include <hip/hip_runtime.h>

namespace {

constexpr int B = 16, C = 3, H = 512, W = 1024;
constexpr int HW = H * W;               // 2^19
constexpr int SLABW = 256, SLABH = 128;
constexpr int XH  = 16;                 // x halo
constexpr int SWD = SLABW + 2 * XH;     // 288 staged cols
constexpr int PADW = SWD + 5;           // 293: row shift 5 banks, gcd(5,32)=1
constexpr int RING = 32;                // ring rows (power of 2)
constexpr int RA = 11;                  // rows behind  (span RA+RB+1+2*RPS... = 32 exact)
constexpr int RB = 16;                  // rows ahead
constexpr int RPS = 4;                  // rows per step
constexpr int BLOCK = 1024;
constexpr int TX = W / SLABW;           // 4
constexpr int TY = H / SLABH;           // 4
constexpr int GRID = B * TX * TY;       // 256 blocks = 1/CU
constexpr int PF_ROWS = RA + RB + 1;    // 28 prefill rows
constexpr int STG_N = C * RPS * SWD;    // 3456 staged elems / step

// 4B-aligned float2 (adjacent-corner pair at arbitrary dword offset)
__device__ __forceinline__ float2 ld2g(const float* p) {
    struct __attribute__((packed, aligned(4))) F2 { float a, b; };
    const F2 v = *reinterpret_cast<const F2*>(p);
    return make_float2(v.a, v.b);
}

__global__ __launch_bounds__(BLOCK, 4) void flow_loss_partial(
    const float* __restrict__ flow,   // (B,H,W,2)
    const float* __restrict__ im1,    // (B,C,H,W)
    const float* __restrict__ im2,    // (B,C,H,W)
    float* __restrict__ partials)     // [GRID]
{
    __shared__ float smem[C * RING * PADW];   // 112512 B -> 1 block/CU
    __shared__ float red[BLOCK / 64];

    const int tid = threadIdx.x;
    const int bid = blockIdx.x;
    const int b   = bid >> 4;                 // 16 slabs per image
    const int tt  = bid & 15;
    const int tyi = tt >> 2;
    const int txi = tt & 3;
    const int xbase  = txi * SLABW;
    const int yStart = tyi * SLABH;

    const float* __restrict__ im1b = im1 + b * C * HW;
    const float* __restrict__ im2b = im2 + b * C * HW;
    const float* __restrict__ flb  = flow + 2 * (b * HW);

    // ---------------- prefill ring: rows yStart-RA .. yStart+RB ----------------
    for (int e = tid; e < PF_ROWS * C * SWD; e += BLOCK) {
        const int scol = e % SWD;
        const int rc   = e / SWD;
        const int c    = rc / PF_ROWS;
        const int ri   = rc - c * PF_ROWS;
        const int row  = yStart - RA + ri;
        if (row >= 0) {                       // row <= yStart+RB < H always
            const int gcol = min(max(xbase - XH + scol, 0), W - 1);
            smem[(c * RING + (row & (RING - 1))) * PADW + scol] =
                im1b[c * HW + row * W + gcol];
        }
    }

    // helper: issue staged loads for rows r0..r0+RPS-1 into regs (no LDS touch)
    auto issue = [&](int r0, int (&sIdx)[4], float (&sVal)[4]) {
#pragma unroll
        for (int k = 0; k < 4; ++k) {
            const int e = k * BLOCK + tid;
            int idx = -1; float v = 0.0f;
            if (e < STG_N) {
                const int scol = e % SWD;
                const int rc   = e / SWD;     // 0..11
                const int c    = rc >> 2;
                const int sr   = rc & 3;
                const int srow = r0 + sr;
                if (srow < H) {
                    const int gcol = min(max(xbase - XH + scol, 0), W - 1);
                    v   = im1b[c * HW + srow * W + gcol];
                    idx = (c * RING + (srow & (RING - 1))) * PADW + scol;
                }
            }
            sIdx[k] = idx; sVal[k] = v;
        }
    };

    // A = staged rows committed at end of the CURRENT step (issued 1 step early)
    int   sIA[4]; float sVA[4];
    issue(yStart + RB + 1, sIA, sVA);

    __syncthreads();                          // prefill visible

    const int colp = tid & (SLABW - 1);
    const int prow = tid >> 8;                // 0..3
    const int x = xbase + colp;

    float acc = 0.0f;

#pragma unroll 1
    for (int ys = yStart; ys < yStart + SLABH; ys += RPS) {
        // ---- issue NEXT step's staged rows (depth-2 prefetch) ----
        int   sIB[4]; float sVB[4];
        issue(ys + RB + 1 + RPS, sIB, sVB);

        // ---- compute this thread's pixel (ring reads rows ys-RA..ys+RB) ----
        const int y = ys + prow;
        const float2 f = *reinterpret_cast<const float2*>(flb + 2 * (y * W + x));

        // replicate reference arithmetic sequence exactly (f32)
        const float base_x = (float)x / (float)W * 2.0f - 1.0f;
        const float base_y = (float)y / (float)H * 2.0f - 1.0f;
        const float gx = f.x / (float)W + base_x;
        const float gy = f.y / (float)H + base_y;
        const float ixf = ((gx + 1.0f) * (float)W - 1.0f) * 0.5f;
        const float iyf = ((gy + 1.0f) * (float)H - 1.0f) * 0.5f;
        const float x0f = floorf(ixf), y0f = floorf(iyf);
        const float wx1 = ixf - x0f, wx0 = 1.0f - wx1;
        const float wy1 = iyf - y0f, wy0 = 1.0f - wy1;
        const int x0 = (int)x0f, y0 = (int)y0f;
        const int x1 = x0 + 1,   y1 = y0 + 1;
        const bool vx0 = (x0 >= 0) & (x0 < W);
        const bool vx1 = (x1 >= 0) & (x1 < W);
        const bool vy0 = (y0 >= 0) & (y0 < H);
        const bool vy1 = (y1 >= 0) & (y1 < H);
        const float w00 = wx0 * wy0 * (float)(vx0 & vy0);
        const float w01 = wx1 * wy0 * (float)(vx1 & vy0);
        const float w10 = wx0 * wy1 * (float)(vx0 & vy1);
        const float w11 = wx1 * wy1 * (float)(vx1 & vy1);
        const int xL  = min(max(x0, 0), W - 2);
        const int x0c = min(max(x0, 0), W - 1);
        const int x1c = min(max(x1, 0), W - 1);
        const int y0c = min(max(y0, 0), H - 1);
        const int y1c = min(max(y1, 0), H - 1);
        const bool s0 = (x0c != xL), s1 = (x1c != xL);
        // fold .x/.y select into weights (exact: selected-away term is 0.0f)
        const float aT0 = (s0 ? 0.0f : w00) + (s1 ? 0.0f : w01);
        const float aT1 = (s0 ? w00 : 0.0f) + (s1 ? w01 : 0.0f);
        const float aB0 = (s0 ? 0.0f : w10) + (s1 ? 0.0f : w11);
        const float aB1 = (s0 ? w10 : 0.0f) + (s1 ? w11 : 0.0f);

        const int jj = xL - xbase + XH;
        const bool inR = (y0c >= ys - RA) & (y1c <= ys + RB) &
                         ((unsigned)jj <= (unsigned)(SWD - 2));

        const int zoff = y * W + x;
        const float z0 = im2b[zoff];
        const float z1 = im2b[HW + zoff];
        const float z2 = im2b[2 * HW + zoff];

        float wp0, wp1, wp2;
        if (inR) {
            const int lT = (y0c & (RING - 1)) * PADW + jj;
            const int lB = (y1c & (RING - 1)) * PADW + jj;
            const float t00 = smem[lT],                   t01 = smem[lT + 1];
            const float b00 = smem[lB],                   b01 = smem[lB + 1];
            const float t10 = smem[RING * PADW + lT],     t11 = smem[RING * PADW + lT + 1];
            const float b10 = smem[RING * PADW + lB],     b11 = smem[RING * PADW + lB + 1];
            const float t20 = smem[2 * RING * PADW + lT], t21 = smem[2 * RING * PADW + lT + 1];
            const float b20 = smem[2 * RING * PADW + lB], b21 = smem[2 * RING * PADW + lB + 1];
            wp0 = ((aT0 * t00 + aT1 * t01) + aB0 * b00) + aB1 * b01;
            wp1 = ((aT0 * t10 + aT1 * t11) + aB0 * b10) + aB1 * b11;
            wp2 = ((aT0 * t20 + aT1 * t21) + aB0 * b20) + aB1 * b21;
        } else {                              // rare (~0.2%/px): exact global path
            const int oT = y0c * W + xL, oB = y1c * W + xL;
            const float2 ta = ld2g(im1b + oT),            ba = ld2g(im1b + oB);
            const float2 tb = ld2g(im1b + HW + oT),       bb = ld2g(im1b + HW + oB);
            const float2 tc = ld2g(im1b + 2 * HW + oT),   bc = ld2g(im1b + 2 * HW + oB);
            wp0 = ((aT0 * ta.x + aT1 * ta.y) + aB0 * ba.x) + aB1 * ba.y;
            wp1 = ((aT0 * tb.x + aT1 * tb.y) + aB0 * bb.x) + aB1 * bb.y;
            wp2 = ((aT0 * tc.x + aT1 * tc.y) + aB0 * bc.x) + aB1 * bc.y;
        }
        acc += fabsf(z0 - wp0) + fabsf(z1 - wp1) + fabsf(z2 - wp2);

        // ---- commit A: slots (rows ys+17..ys+20 -> old ys-15..ys-12) are
        // disjoint from every row read this step (ys-11..ys+16), so no
        // read/write race within the step; one barrier orders step->step. ----
#pragma unroll
        for (int k = 0; k < 4; ++k)
            if (sIA[k] >= 0) smem[sIA[k]] = sVA[k];
        __syncthreads();

#pragma unroll
        for (int k = 0; k < 4; ++k) { sIA[k] = sIB[k]; sVA[k] = sVB[k]; }
    }

    // ---------------- block reduction ----------------
#pragma unroll
    for (int o = 32; o > 0; o >>= 1)
        acc += __shfl_down(acc, o, 64);
    const int lane = tid & 63;
    const int wid  = tid >> 6;
    if (lane == 0) red[wid] = acc;
    __syncthreads();
    if (tid == 0) {
        float s = 0.0f;
#pragma unroll
        for (int wv = 0; wv < BLOCK / 64; ++wv) s += red[wv];
        partials[bid] = s;
    }
}

__global__ __launch_bounds__(256) void flow_loss_reduce(
    const float* __restrict__ partials, float* __restrict__ out)
{
    __shared__ double lds[256];
    double s = 0.0;
    for (int i = threadIdx.x; i < GRID; i += 256) s += (double)partials[i];
    lds[threadIdx.x] = s;
    __syncthreads();
    for (int o = 128; o > 0; o >>= 1) {
        if (threadIdx.x < o) lds[threadIdx.x] += lds[threadIdx.x + o];
        __syncthreads();
    }
    if (threadIdx.x == 0) out[0] = (float)(lds[0] / (double)(W * H));
}

} // namespace

extern "C" void kernel_launch(void* const* d_in, const int* in_sizes, int n_in,
                              void* d_out, int out_size, void* d_ws, size_t ws_size,
                              hipStream_t stream) {
    const float* flow = (const float*)d_in[0];
    const float* im1  = (const float*)d_in[1];
    const float* im2  = (const float*)d_in[2];
    float* out = (float*)d_out;
    float* partials = (float*)d_ws;

    flow_loss_partial<<<GRID, BLOCK, 0, stream>>>(flow, im1, im2, partials);
    flow_loss_reduce<<<1, 256, 0, stream>>>(partials, out);
}

// Round 8
// 64.603 us; speedup vs baseline: 9.8546x; 1.0409x over previous
//
#include <hip/hip_runtime.h>

namespace {

constexpr int B = 16, C = 3, H = 512, W = 1024;
constexpr int HW = H * W;               // 2^19
constexpr int SLABW = 256, SLABH = 128;
constexpr int XH  = 16;                 // x halo
constexpr int SWD = SLABW + 2 * XH;     // 288 staged cols
constexpr int PADW = SWD + 5;           // 293
constexpr int RING = 32;                // ring rows (power of 2)
constexpr int RA = 11;                  // rows behind
constexpr int RB = 16;                  // rows ahead
constexpr int RPS = 4;                  // rows per step
constexpr int BLOCK = 1024;
constexpr int TX = W / SLABW;           // 4
constexpr int TY = H / SLABH;           // 4
constexpr int GRID = B * TX * TY;       // 256 blocks = 1/CU
constexpr int PF_ROWS = RA + RB + 1;    // 28 prefill rows
constexpr int STG_N = C * RPS * SWD;    // 3456 staged elems / step

constexpr float INV_W = 1.0f / 1024.0f;
constexpr float INV_H = 1.0f / 512.0f;

// 4B-aligned float2 (adjacent-corner pair at arbitrary dword offset)
__device__ __forceinline__ float2 ld2g(const float* p) {
    struct __attribute__((packed, aligned(4))) F2 { float a, b; };
    const F2 v = *reinterpret_cast<const F2*>(p);
    return make_float2(v.a, v.b);
}

__global__ __launch_bounds__(BLOCK, 4) void flow_loss_partial(
    const float* __restrict__ flow,   // (B,H,W,2)
    const float* __restrict__ im1,    // (B,C,H,W)
    const float* __restrict__ im2,    // (B,C,H,W)
    float* __restrict__ partials)     // [GRID]
{
    __shared__ float smem[C * RING * PADW];   // 112512 B -> 1 block/CU
    __shared__ float red[BLOCK / 64];

    const int tid = threadIdx.x;
    const int bid = blockIdx.x;
    const int b   = bid >> 4;                 // 16 slabs per image
    const int tt  = bid & 15;
    const int tyi = tt >> 2;
    const int txi = tt & 3;
    const int xbase  = txi * SLABW;
    const int yStart = tyi * SLABH;

    const float* __restrict__ im1b = im1 + b * C * HW;
    const float* __restrict__ im2b = im2 + b * C * HW;
    const float* __restrict__ flb  = flow + 2 * (b * HW);

    // ---------------- prefill ring: rows yStart-RA .. yStart+RB ----------------
    for (int e = tid; e < PF_ROWS * C * SWD; e += BLOCK) {
        const int scol = e % SWD;
        const int rc   = e / SWD;
        const int c    = rc / PF_ROWS;
        const int ri   = rc - c * PF_ROWS;
        const int row  = yStart - RA + ri;
        if (row >= 0) {                       // row <= yStart+RB < H always
            const int gcol = min(max(xbase - XH + scol, 0), W - 1);
            smem[(c * RING + (row & (RING - 1))) * PADW + scol] =
                im1b[c * HW + row * W + gcol];
        }
    }

    // ---- hoisted staging descriptors (tid-dependent only) ----
    int  stSr[4], stGBase[4], stLBase[4];
    bool stOK[4];
#pragma unroll
    for (int k = 0; k < 4; ++k) {
        const int e = k * BLOCK + tid;
        stOK[k] = (e < STG_N);
        const int ec   = stOK[k] ? e : 0;
        const int scol = ec % SWD;
        const int rc   = ec / SWD;            // 0..11
        const int c    = rc >> 2;
        stSr[k]   = rc & 3;
        const int gcol = min(max(xbase - XH + scol, 0), W - 1);
        stGBase[k] = c * HW + gcol;
        stLBase[k] = (c * RING) * PADW + scol;
    }

    // issue staged loads for rows r0..r0+RPS-1 into regs (no LDS touch)
    auto issue = [&](int r0, int (&sIdx)[4], float (&sVal)[4]) {
#pragma unroll
        for (int k = 0; k < 4; ++k) {
            const int srow = r0 + stSr[k];
            int idx = -1; float v = 0.0f;
            if (stOK[k] & (srow < H)) {
                v   = im1b[stGBase[k] + (srow << 10)];
                idx = stLBase[k] + (srow & (RING - 1)) * PADW;
            }
            sIdx[k] = idx; sVal[k] = v;
        }
    };

    // A = staged rows committed at end of the CURRENT step (issued 1 step early)
    int   sIA[4]; float sVA[4];
    issue(yStart + RB + 1, sIA, sVA);

    __syncthreads();                          // prefill visible

    const int colp = tid & (SLABW - 1);
    const int prow = tid >> 8;                // 0..3
    const int x = xbase + colp;
    // exact: x has <=10 mantissa bits; pow-2 scale and -1 are exact
    const float base_x = (float)x * (2.0f * INV_W) - 1.0f;

    float acc = 0.0f;

#pragma unroll 1
    for (int ys = yStart; ys < yStart + SLABH; ys += RPS) {
        // ---- issue NEXT step's staged rows (depth-2 prefetch) ----
        int   sIB[4]; float sVB[4];
        issue(ys + RB + 1 + RPS, sIB, sVB);

        // ---- compute this thread's pixel (ring reads rows ys-RA..ys+RB) ----
        const int y = ys + prow;
        const float2 f = *reinterpret_cast<const float2*>(flb + 2 * (y * W + x));

        // bit-exact compressed index math (see proof in commit note):
        //   gx  = RN(f.x/W + base_x)  ==  fmaf(f.x, 1/W, base_x)
        //   ix  = ((gx+1)*W - 1)*0.5  ==  fmaf(gx+1, W/2, -0.5)   (all-exact given gx+1)
        const float base_y = (float)y * (2.0f * INV_H) - 1.0f;  // exact
        const float gx = __builtin_fmaf(f.x, INV_W, base_x);
        const float gy = __builtin_fmaf(f.y, INV_H, base_y);
        const float ixf = __builtin_fmaf(gx + 1.0f, 512.0f, -0.5f);
        const float iyf = __builtin_fmaf(gy + 1.0f, 256.0f, -0.5f);

        const float x0f = floorf(ixf), y0f = floorf(iyf);
        const float wx1 = ixf - x0f, wx0 = 1.0f - wx1;
        const float wy1 = iyf - y0f, wy0 = 1.0f - wy1;
        const int x0 = (int)x0f, y0 = (int)y0f;
        const int x1 = x0 + 1,   y1 = y0 + 1;
        const bool vx0 = (x0 >= 0) & (x0 < W);
        const bool vx1 = (x1 >= 0) & (x1 < W);
        const bool vy0 = (y0 >= 0) & (y0 < H);
        const bool vy1 = (y1 >= 0) & (y1 < H);
        const float w00 = wx0 * wy0 * (float)(vx0 & vy0);
        const float w01 = wx1 * wy0 * (float)(vx1 & vy0);
        const float w10 = wx0 * wy1 * (float)(vx0 & vy1);
        const float w11 = wx1 * wy1 * (float)(vx1 & vy1);
        const int xL  = min(max(x0, 0), W - 2);
        const int x0c = min(max(x0, 0), W - 1);
        const int x1c = min(max(x1, 0), W - 1);
        const int y0c = min(max(y0, 0), H - 1);
        const int y1c = min(max(y1, 0), H - 1);
        const bool s0 = (x0c != xL), s1 = (x1c != xL);
        // fold .x/.y select into weights (exact: selected-away term is 0.0f)
        const float aT0 = (s0 ? 0.0f : w00) + (s1 ? 0.0f : w01);
        const float aT1 = (s0 ? w00 : 0.0f) + (s1 ? w01 : 0.0f);
        const float aB0 = (s0 ? 0.0f : w10) + (s1 ? 0.0f : w11);
        const float aB1 = (s0 ? w10 : 0.0f) + (s1 ? w11 : 0.0f);

        const int jj = xL - xbase + XH;
        const bool inR = (y0c >= ys - RA) & (y1c <= ys + RB) &
                         ((unsigned)jj <= (unsigned)(SWD - 2));

        const int zoff = y * W + x;
        const float z0 = im2b[zoff];
        const float z1 = im2b[HW + zoff];
        const float z2 = im2b[2 * HW + zoff];

        float wp0, wp1, wp2;
        if (inR) {
            const int lT = (y0c & (RING - 1)) * PADW + jj;
            const int lB = (y1c & (RING - 1)) * PADW + jj;
            const float t00 = smem[lT],                   t01 = smem[lT + 1];
            const float b00 = smem[lB],                   b01 = smem[lB + 1];
            const float t10 = smem[RING * PADW + lT],     t11 = smem[RING * PADW + lT + 1];
            const float b10 = smem[RING * PADW + lB],     b11 = smem[RING * PADW + lB + 1];
            const float t20 = smem[2 * RING * PADW + lT], t21 = smem[2 * RING * PADW + lT + 1];
            const float b20 = smem[2 * RING * PADW + lB], b21 = smem[2 * RING * PADW + lB + 1];
            wp0 = ((aT0 * t00 + aT1 * t01) + aB0 * b00) + aB1 * b01;
            wp1 = ((aT0 * t10 + aT1 * t11) + aB0 * b10) + aB1 * b11;
            wp2 = ((aT0 * t20 + aT1 * t21) + aB0 * b20) + aB1 * b21;
        } else {                              // rare (~0.6%/px): exact global path
            const int oT = y0c * W + xL, oB = y1c * W + xL;
            const float2 ta = ld2g(im1b + oT),            ba = ld2g(im1b + oB);
            const float2 tb = ld2g(im1b + HW + oT),       bb = ld2g(im1b + HW + oB);
            const float2 tc = ld2g(im1b + 2 * HW + oT),   bc = ld2g(im1b + 2 * HW + oB);
            wp0 = ((aT0 * ta.x + aT1 * ta.y) + aB0 * ba.x) + aB1 * ba.y;
            wp1 = ((aT0 * tb.x + aT1 * tb.y) + aB0 * bb.x) + aB1 * bb.y;
            wp2 = ((aT0 * tc.x + aT1 * tc.y) + aB0 * bc.x) + aB1 * bc.y;
        }
        acc += fabsf(z0 - wp0) + fabsf(z1 - wp1) + fabsf(z2 - wp2);

        // ---- commit A: written slots are disjoint from all rows read this
        // step (proof in round-7 note); one barrier orders step->step. ----
#pragma unroll
        for (int k = 0; k < 4; ++k)
            if (sIA[k] >= 0) smem[sIA[k]] = sVA[k];
        __syncthreads();

#pragma unroll
        for (int k = 0; k < 4; ++k) { sIA[k] = sIB[k]; sVA[k] = sVB[k]; }
    }

    // ---------------- block reduction ----------------
#pragma unroll
    for (int o = 32; o > 0; o >>= 1)
        acc += __shfl_down(acc, o, 64);
    const int lane = tid & 63;
    const int wid  = tid >> 6;
    if (lane == 0) red[wid] = acc;
    __syncthreads();
    if (tid == 0) {
        float s = 0.0f;
#pragma unroll
        for (int wv = 0; wv < BLOCK / 64; ++wv) s += red[wv];
        partials[bid] = s;
    }
}

__global__ __launch_bounds__(256) void flow_loss_reduce(
    const float* __restrict__ partials, float* __restrict__ out)
{
    __shared__ double lds[256];
    double s = 0.0;
    for (int i = threadIdx.x; i < 256; i += 256) {}   // no-op, keep shape
    double acc = 0.0;
    for (int i = threadIdx.x; i < GRID; i += 256) acc += (double)partials[i];
    lds[threadIdx.x] = acc;
    __syncthreads();
    for (int o = 128; o > 0; o >>= 1) {
        if (threadIdx.x < o) lds[threadIdx.x] += lds[threadIdx.x + o];
        __syncthreads();
    }
    if (threadIdx.x == 0) out[0] = (float)(lds[0] / (double)(W * H));
    (void)s;
}

} // namespace

extern "C" void kernel_launch(void* const* d_in, const int* in_sizes, int n_in,
                              void* d_out, int out_size, void* d_ws, size_t ws_size,
                              hipStream_t stream) {
    const float* flow = (const float*)d_in[0];
    const float* im1  = (const float*)d_in[1];
    const float* im2  = (const float*)d_in[2];
    float* out = (float*)d_out;
    float* partials = (float*)d_ws;

    flow_loss_partial<<<GRID, BLOCK, 0, stream>>>(flow, im1, im2, partials);
    flow_loss_reduce<<<1, 256, 0, stream>>>(partials, out);
}